// Round 10
// baseline (127.250 us; speedup 1.0000x reference)
//
#include <hip/hip_runtime.h>
#include <math.h>

#define NB 4
#define HH 16
#define SS 1024
#define DD 64
#define NKST 16   // SS / 64

typedef __attribute__((ext_vector_type(8))) short bf16x8;
typedef __attribute__((ext_vector_type(4))) float f32x4;

static __device__ __forceinline__ short f2bf(float f) {
    __bf16 h = (__bf16)f;
    return __builtin_bit_cast(short, h);
}
static __device__ __forceinline__ float bflo(int w) {
    return __builtin_bit_cast(float, (unsigned)w << 16);
}
static __device__ __forceinline__ float bfhi(int w) {
    return __builtin_bit_cast(float, (unsigned)w & 0xffff0000u);
}
static __device__ __forceinline__ float bfu(unsigned short u) {
    return __builtin_bit_cast(float, (unsigned)u << 16);
}
// P LDS: [pos = q*64 + k][8 u32 head-pairs], XOR swizzle.
static __device__ __forceinline__ int pidx(int pos, int hp) {
    int s = ((pos >> 2) & 3) | (((pos >> 9) & 1) << 2);
    return pos * 8 + (hp ^ s);
}
// M LDS: [16 g][16 q x 32 k-pairs u32], XOR on 16B groups.
static __device__ __forceinline__ int midx(int g, int loc, int x3) {
    return g * 512 + ((((loc >> 2) ^ x3) << 2) | (loc & 3));
}

static __device__ __forceinline__ bf16x8 load8_bf16(const float* p) {
    const float4* p4 = reinterpret_cast<const float4*>(p);
    float4 a = p4[0], b = p4[1];
    bf16x8 f;
    f[0]=f2bf(a.x); f[1]=f2bf(a.y); f[2]=f2bf(a.z); f[3]=f2bf(a.w);
    f[4]=f2bf(b.x); f[5]=f2bf(b.y); f[6]=f2bf(b.z); f[7]=f2bf(b.w);
    return f;
}

// ---------- merged prep: K -> frag-major bf16, V -> frag-major transposed bf16 ----------
__global__ __launch_bounds__(256) void prep_all(const float* __restrict__ xk,
                                                short* __restrict__ kfr,
                                                const float* __restrict__ xv,
                                                short* __restrict__ vfr) {
    __shared__ float T[64][65];
    const int bid = blockIdx.x;
    const int t = threadIdx.x;
    if (bid < 2048) {
        // K path: chunk c = ((((b*16+h)*16+kst)*4+kt)*2+ds)*64 + lane
        int c = bid * 256 + t;
        int lane = c & 63, ds = (c >> 6) & 1, kt = (c >> 7) & 3;
        int kst = (c >> 9) & 15, h = (c >> 13) & 15, b = c >> 17;
        const float* src = xk + ((size_t)((b * HH + h) * SS) + kst * 64 + kt * 16 + (lane & 15)) * DD
                              + ds * 32 + (lane >> 4) * 8;
        *(reinterpret_cast<bf16x8*>(kfr) + c) = load8_bf16(src);
    } else {
        // V path: tile = (b*16+h)*16 + kst, via LDS transpose
        int tile = bid - 2048;
        const float* src = xv + ((size_t)(tile >> 4) * SS + (tile & 15) * 64) * DD;
        int row = t >> 2, col = (t & 3) * 16;
#pragma unroll
        for (int ii = 0; ii < 4; ++ii) {
            float4 v = *reinterpret_cast<const float4*>(src + row * DD + col + ii * 4);
            T[row][col + ii*4] = v.x; T[row][col + ii*4 + 1] = v.y;
            T[row][col + ii*4 + 2] = v.z; T[row][col + ii*4 + 3] = v.w;
        }
        __syncthreads();
#pragma unroll
        for (int jj = 0; jj < 2; ++jj) {
            int c2 = t * 2 + jj;
            int lane = c2 & 63, nt = (c2 >> 6) & 3, kc = (c2 >> 8) & 1;
            bf16x8 o;
#pragma unroll
            for (int i = 0; i < 8; ++i)
                o[i] = f2bf(T[kc * 32 + (lane >> 4) * 8 + i][nt * 16 + (lane & 15)]);
            *(reinterpret_cast<bf16x8*>(vfr) + (size_t)tile * 512 + c2) = o;
        }
    }
}

// One block = (b, qt-pair pp, kpar), 16 waves. Processes qt=63-pp then qt=pp,
// k-steps of parity kpar only. Phase1+mix computed once per (b,qt,kst).
// K regs prefetched one step ahead; V loaded in one batch pre-sync1 (R7 form).
// __launch_bounds__(1024) with NO min-waves arg: empirically, specifying the
// 2nd arg caps the allocator at 64 VGPR (R8/R9 spilled: WRITE 53->109 MB);
// plain form allows ~128 (R1 measured 128).
__global__ __launch_bounds__(1024) void hca_fused(
    const float* __restrict__ xq, const short* __restrict__ kfr,
    const short* __restrict__ vfr, const float* __restrict__ Wm,
    const int* __restrict__ causalp, unsigned short* __restrict__ ppO,
    float2* __restrict__ ppml)
{
    __shared__ int Pbuf[8192];   // 32 KB
    __shared__ int Mbuf[8192];   // 32 KB

    const int tid  = threadIdx.x;
    const int lane = tid & 63;
    const int w    = tid >> 6;     // 0..15
    const int l15  = lane & 15;
    const int lg   = lane >> 4;

    const int bid  = blockIdx.x;           // 256 blocks: b(2) | pp(5) | kpar(1)
    const int b    = bid & 3;              // b fixed per XCD
    const int pp   = (bid >> 2) & 31;
    const int kpar = (bid >> 7) & 1;

    const int causal = causalp[0];
    const int hp = w & 7;          // phase-1 head pair
    const int kh = w >> 3;         // phase-1 kt half
    const int g  = w;              // phase-2 output head

    const float LOG2E = 1.44269504088896f;

    // W B-frag for mix MFMA (K=16 used, zero-padded)
    bf16x8 wt = {0,0,0,0,0,0,0,0};
    if (lg < 2) {
#pragma unroll
        for (int ii = 0; ii < 8; ++ii)
            wt[ii] = f2bf(Wm[l15 * 16 + lg * 8 + ii] * 0.125f * LOG2E);
    }

    const short* vb0 = vfr + (size_t)(b * HH + g) * NKST * 8 * 512 + lane * 8;
    const short* kb0 = kfr + (size_t)(b * HH + 2 * hp) * NKST * 8 * 512 + lane * 8;

#pragma unroll 1
    for (int seg = 0; seg < 2; ++seg) {
        const int qt = seg ? pp : 63 - pp;
        const int q0 = qt << 4;
        const int pairIdx = b * 64 + qt;

        // Q A-frags for phase-1 heads (2hp, 2hp+1)
        bf16x8 qf[2][2];
#pragma unroll
        for (int hi = 0; hi < 2; ++hi) {
            const float* qp = xq + ((size_t)(b * HH + 2 * hp + hi) * SS + q0 + l15) * DD + lg * 8;
#pragma unroll
            for (int ds = 0; ds < 2; ++ds) qf[hi][ds] = load8_bf16(qp + ds * 32);
        }

        f32x4 oacc[4];
#pragma unroll
        for (int nt = 0; nt < 4; ++nt) oacc[nt] = (f32x4){0.f, 0.f, 0.f, 0.f};
        float mrun = -INFINITY, lrun = 0.f;

        const int nkf = causal ? ((q0 + 16 + 63) >> 6) : NKST;

        // K prologue: prefetch first step's fragments
        bf16x8 kA[2][2], kB[2][2];   // [kt2][ds] for head 2hp / 2hp+1
        {
            const short* kbase = kb0 + (size_t)kpar * 8 * 512;
#pragma unroll
            for (int kt2 = 0; kt2 < 2; ++kt2)
#pragma unroll
                for (int ds = 0; ds < 2; ++ds) {
                    const int kt = kh * 2 + kt2;
                    kA[kt2][ds] = *reinterpret_cast<const bf16x8*>(kbase + (kt*2 + ds) * 512);
                    kB[kt2][ds] = *reinterpret_cast<const bf16x8*>(kbase + (NKST*8 + kt*2 + ds) * 512);
                }
        }

#pragma unroll 1
        for (int kst = kpar; kst < nkf; kst += 2) {
            const int k0 = kst << 6;

            // ---------- phase1: QK^T with resident K regs ----------
            __builtin_amdgcn_s_setprio(1);
#pragma unroll
            for (int kt2 = 0; kt2 < 2; ++kt2) {
                const int kt = kh * 2 + kt2;
                f32x4 a0 = (f32x4){0.f,0.f,0.f,0.f}, a1 = a0;
#pragma unroll
                for (int ds = 0; ds < 2; ++ds) {
                    a0 = __builtin_amdgcn_mfma_f32_16x16x32_bf16(qf[0][ds], kA[kt2][ds], a0, 0, 0, 0);
                    a1 = __builtin_amdgcn_mfma_f32_16x16x32_bf16(qf[1][ds], kB[kt2][ds], a1, 0, 0, 0);
                }
#pragma unroll
                for (int r = 0; r < 4; ++r) {
                    int pos = (lg * 4 + r) * 64 + kt * 16 + l15;
                    int pk = (int)(unsigned short)f2bf(a0[r]) | ((int)(unsigned short)f2bf(a1[r]) << 16);
                    Pbuf[pidx(pos, hp)] = pk;
                }
            }
            __builtin_amdgcn_s_setprio(0);

            // issue NEXT step's K loads (same regs; land during sync1+mix+sync2+phase2)
            {
                const int kstn = (kst + 2 < nkf) ? (kst + 2) : kst;
                const short* kbase = kb0 + (size_t)kstn * 8 * 512;
#pragma unroll
                for (int kt2 = 0; kt2 < 2; ++kt2)
#pragma unroll
                    for (int ds = 0; ds < 2; ++ds) {
                        const int kt = kh * 2 + kt2;
                        kA[kt2][ds] = *reinterpret_cast<const bf16x8*>(kbase + (kt*2 + ds) * 512);
                        kB[kt2][ds] = *reinterpret_cast<const bf16x8*>(kbase + (NKST*8 + kt*2 + ds) * 512);
                    }
            }
            // V loads: one batch (R7 form), covered by mix + barriers
            const short* vbase = vb0 + (size_t)kst * 8 * 512;
            bf16x8 vf[8];
#pragma unroll
            for (int kc = 0; kc < 2; ++kc)
#pragma unroll
                for (int nt = 0; nt < 4; ++nt)
                    vf[kc * 4 + nt] = *reinterpret_cast<const bf16x8*>(vbase + (kc*4 + nt) * 512);

            __syncthreads();   // sync1: P ready (also fences prev phase2 M-reads)

            // ---------- phase1.5: head-mix MFMA; wave w -> q-row w ----------
#pragma unroll
            for (int m = 0; m < 4; ++m) {
                const int c = w * 4 + m;
                const int pos = c * 16 + l15;
                int4 ia = {0, 0, 0, 0};
                if (lg < 2) {
                    ia.x = Pbuf[pidx(pos, lg * 4 + 0)];
                    ia.y = Pbuf[pidx(pos, lg * 4 + 1)];
                    ia.z = Pbuf[pidx(pos, lg * 4 + 2)];
                    ia.w = Pbuf[pidx(pos, lg * 4 + 3)];
                }
                bf16x8 A = __builtin_bit_cast(bf16x8, ia);
                f32x4 cc = (f32x4){0.f, 0.f, 0.f, 0.f};
                cc = __builtin_amdgcn_mfma_f32_16x16x32_bf16(A, wt, cc, 0, 0, 0);
                int loc = w * 32 + (c & 3) * 8 + lg * 2;
                int x3 = (w + l15) & 7;
                int u0 = (int)(unsigned short)f2bf(cc[0]) | ((int)(unsigned short)f2bf(cc[1]) << 16);
                int u1 = (int)(unsigned short)f2bf(cc[2]) | ((int)(unsigned short)f2bf(cc[3]) << 16);
                *reinterpret_cast<int2*>(&Mbuf[midx(l15, loc, x3)]) = make_int2(u0, u1);
            }
            __syncthreads();   // sync2: M ready

            // ---------- phase2: softmax (log2) + PV for head g = w ----------
            const int x3r = (l15 + g) & 7;
            int4 rA = *reinterpret_cast<const int4*>(&Mbuf[midx(g, l15 * 32 + lg * 4, x3r)]);
            int4 rB = *reinterpret_cast<const int4*>(&Mbuf[midx(g, l15 * 32 + 16 + lg * 4, x3r)]);

            float sm[16];
#pragma unroll
            for (int jj = 0; jj < 4; ++jj) {
                sm[2*jj]     = bflo(rA[jj]);  sm[2*jj + 1] = bfhi(rA[jj]);
                sm[8 + 2*jj] = bflo(rB[jj]);  sm[9 + 2*jj] = bfhi(rB[jj]);
            }
            if (causal && kst == nkf - 1) {
#pragma unroll
                for (int jj = 0; jj < 16; ++jj) {
                    int kk = (jj < 8) ? (lg * 8 + jj) : (32 + lg * 8 + (jj - 8));
                    if (k0 + kk > q0 + l15) sm[jj] = -INFINITY;
                }
            }

            float mx[4];
#pragma unroll
            for (int t = 0; t < 4; ++t)
                mx[t] = fmaxf(fmaxf(sm[4*t], sm[4*t+1]), fmaxf(sm[4*t+2], sm[4*t+3]));
            float mt = fmaxf(fmaxf(mx[0], mx[1]), fmaxf(mx[2], mx[3]));
            mt = fmaxf(mt, __shfl_xor(mt, 16));
            mt = fmaxf(mt, __shfl_xor(mt, 32));

            if (__any(mt > mrun + 8.0f)) {            // defer-rescale
                float mnew = fmaxf(mrun, mt);
                float scl = __builtin_amdgcn_exp2f(mrun - mnew);
                mrun = mnew;
                lrun *= scl;
                int scli = __builtin_bit_cast(int, scl);
#pragma unroll
                for (int r = 0; r < 4; ++r) {
                    int v = __builtin_amdgcn_ds_bpermute((lg * 4 + r) * 4, scli);
                    float s = __builtin_bit_cast(float, v);
#pragma unroll
                    for (int nt = 0; nt < 4; ++nt) oacc[nt][r] *= s;
                }
            }

#pragma unroll
            for (int jj = 0; jj < 16; ++jj) sm[jj] = __builtin_amdgcn_exp2f(sm[jj] - mrun);
            float s0 = ((sm[0]+sm[1]) + (sm[2]+sm[3])) + ((sm[4]+sm[5]) + (sm[6]+sm[7]));
            float s1 = ((sm[8]+sm[9]) + (sm[10]+sm[11])) + ((sm[12]+sm[13]) + (sm[14]+sm[15]));
            lrun += s0 + s1;

            int paw[8];
#pragma unroll
            for (int t = 0; t < 8; ++t)
                paw[t] = (int)(unsigned short)f2bf(sm[2*t]) | ((int)(unsigned short)f2bf(sm[2*t+1]) << 16);
            bf16x8 pa0 = __builtin_bit_cast(bf16x8, *(int4*)&paw[0]);
            bf16x8 pa1 = __builtin_bit_cast(bf16x8, *(int4*)&paw[4]);

            __builtin_amdgcn_s_setprio(1);
#pragma unroll
            for (int nt = 0; nt < 4; ++nt)
                oacc[nt] = __builtin_amdgcn_mfma_f32_16x16x32_bf16(pa0, vf[nt], oacc[nt], 0, 0, 0);
#pragma unroll
            for (int nt = 0; nt < 4; ++nt)
                oacc[nt] = __builtin_amdgcn_mfma_f32_16x16x32_bf16(pa1, vf[4 + nt], oacc[nt], 0, 0, 0);
            __builtin_amdgcn_s_setprio(0);
            // no trailing barrier: sync1(t+1) fences M-reads vs next M-writes.
        }

        // ---------- epilogue: normalized bf16 partial O + (m,l) ----------
        float lt = lrun;
        lt += __shfl_xor(lt, 16);
        lt += __shfl_xor(lt, 32);
        if (lg == 0)
            ppml[(((size_t)pairIdx * 2 + kpar) * 16 + g) * 16 + l15] = make_float2(mrun, lt);
        float rl = (lt > 0.f) ? (1.0f / lt) : 0.f;
        int rli = __builtin_bit_cast(int, rl);
        size_t obase = (((size_t)pairIdx * 2 + kpar) * 16 + g) * 1024;
#pragma unroll
        for (int r = 0; r < 4; ++r) {
            int v = __builtin_amdgcn_ds_bpermute((lg * 4 + r) * 4, rli);
            float linv = __builtin_bit_cast(float, v);
            int q = lg * 4 + r;
#pragma unroll
            for (int nt = 0; nt < 4; ++nt)
                ppO[obase + q * 64 + nt * 16 + l15] =
                    (unsigned short)f2bf(oacc[nt][r] * linv);
        }
        __syncthreads();   // LDS quiesce before next segment reuses P/M
    }
}

// ---------- combine: merge the 2 k-parity partials per (b,qt) ----------
__global__ __launch_bounds__(256) void hca_combine(
    const unsigned short* __restrict__ ppO, const float2* __restrict__ ppml,
    float* __restrict__ out)
{
    const int pairIdx = blockIdx.x;        // b*64 + qt
    const int b = pairIdx >> 6, qt = pairIdx & 63;
    const int t = threadIdx.x;
    const int g = t >> 4, dc = t & 15;

    const size_t o0 = (((size_t)pairIdx * 2 + 0) * 16 + g) * 1024;
    const size_t o1 = (((size_t)pairIdx * 2 + 1) * 16 + g) * 1024;
    const float2* ml0p = ppml + (((size_t)pairIdx * 2 + 0) * 16 + g) * 16;
    const float2* ml1p = ppml + (((size_t)pairIdx * 2 + 1) * 16 + g) * 16;

#pragma unroll 4
    for (int q = 0; q < 16; ++q) {
        float2 ml0 = ml0p[q], ml1 = ml1p[q];
        float ms = fmaxf(ml0.x, ml1.x);
        float w0 = ml0.y * exp2f(ml0.x - ms);
        float w1 = ml1.y * exp2f(ml1.x - ms);
        float rs = 1.0f / (w0 + w1);
        float a0 = w0 * rs, a1 = w1 * rs;
        ushort4 u0 = *reinterpret_cast<const ushort4*>(ppO + o0 + q * 64 + dc * 4);
        ushort4 u1 = *reinterpret_cast<const ushort4*>(ppO + o1 + q * 64 + dc * 4);
        float4 res;
        res.x = a0 * bfu(u0.x) + a1 * bfu(u1.x);
        res.y = a0 * bfu(u0.y) + a1 * bfu(u1.y);
        res.z = a0 * bfu(u0.z) + a1 * bfu(u1.z);
        res.w = a0 * bfu(u0.w) + a1 * bfu(u1.w);
        *reinterpret_cast<float4*>(out + (((size_t)b * SS + qt * 16 + q) * HH + g) * DD + dc * 4) = res;
    }
}

extern "C" void kernel_launch(void* const* d_in, const int* in_sizes, int n_in,
                              void* d_out, int out_size, void* d_ws, size_t ws_size,
                              hipStream_t stream) {
    const float* xq = (const float*)d_in[0];
    const float* xk = (const float*)d_in[1];
    const float* xv = (const float*)d_in[2];
    const float* Wm = (const float*)d_in[3];
    const int* causal = (const int*)d_in[4];
    float* out = (float*)d_out;

    short* vfr = (short*)d_ws;                               // 8 MB fragment-major V
    short* kfr = vfr + (size_t)NB * HH * SS * DD;            // 8 MB fragment-major K
    unsigned short* ppO = (unsigned short*)(kfr + (size_t)NB * HH * SS * DD);  // 16 MB
    float2* ppml = (float2*)(ppO + (size_t)512 * 16 * 1024); // 1 MB

    prep_all<<<2048 + NB * HH * NKST, 256, 0, stream>>>(xk, kfr, xv, vfr);

    hca_fused<<<256, 1024, 0, stream>>>(xq, kfr, vfr, Wm, causal, ppO, ppml);
    hca_combine<<<256, 256, 0, stream>>>(ppO, ppml, out);
}

// Round 11
// 100.893 us; speedup vs baseline: 1.2612x; 1.2612x over previous
//
#include <hip/hip_runtime.h>
#include <math.h>

#define NB 4
#define HH 16
#define SS 1024
#define DD 64
#define NKST 16   // SS / 64
#define QB 32     // q-tile rows

typedef __attribute__((ext_vector_type(8))) short bf16x8;
typedef __attribute__((ext_vector_type(4))) float f32x4;

static __device__ __forceinline__ short f2bf(float f) {
    __bf16 h = (__bf16)f;
    return __builtin_bit_cast(short, h);
}
static __device__ __forceinline__ float bflo(int w) {
    return __builtin_bit_cast(float, (unsigned)w << 16);
}
static __device__ __forceinline__ float bfhi(int w) {
    return __builtin_bit_cast(float, (unsigned)w & 0xffff0000u);
}
static __device__ __forceinline__ float bfu(unsigned short u) {
    return __builtin_bit_cast(float, (unsigned)u << 16);
}
// P LDS: [pos = q*64 + k][16 h as 8 u32 pairs], pos in 0..2047, XOR swizzle.
// writer 2-way (free), mix reader conflict-free (q extended to 5 bits; only
// bit9 of pos enters s -> per-inst-constant for the reader, lane-varying for
// the writer: same conflict classes as the validated QB=16 version).
static __device__ __forceinline__ int pidx(int pos, int hp) {
    int s = ((pos >> 2) & 3) | (((pos >> 9) & 1) << 2);
    return pos * 8 + (hp ^ s);
}
// M LDS: [8 gl][1024 u32 = 32 q x 32 k-pairs], XOR on 16B groups.
static __device__ __forceinline__ int midx(int gl, int loc, int x3) {
    return gl * 1024 + ((((loc >> 2) ^ x3) << 2) | (loc & 3));
}

static __device__ __forceinline__ bf16x8 load8_bf16(const float* p) {
    const float4* p4 = reinterpret_cast<const float4*>(p);
    float4 a = p4[0], b = p4[1];
    bf16x8 f;
    f[0]=f2bf(a.x); f[1]=f2bf(a.y); f[2]=f2bf(a.z); f[3]=f2bf(a.w);
    f[4]=f2bf(b.x); f[5]=f2bf(b.y); f[6]=f2bf(b.z); f[7]=f2bf(b.w);
    return f;
}

// ---------- merged prep: K -> frag-major bf16, V -> frag-major transposed bf16 ----------
__global__ __launch_bounds__(256) void prep_all(const float* __restrict__ xk,
                                                short* __restrict__ kfr,
                                                const float* __restrict__ xv,
                                                short* __restrict__ vfr) {
    __shared__ float T[64][65];
    const int bid = blockIdx.x;
    const int t = threadIdx.x;
    if (bid < 2048) {
        int c = bid * 256 + t;
        int lane = c & 63, ds = (c >> 6) & 1, kt = (c >> 7) & 3;
        int kst = (c >> 9) & 15, h = (c >> 13) & 15, b = c >> 17;
        const float* src = xk + ((size_t)((b * HH + h) * SS) + kst * 64 + kt * 16 + (lane & 15)) * DD
                              + ds * 32 + (lane >> 4) * 8;
        *(reinterpret_cast<bf16x8*>(kfr) + c) = load8_bf16(src);
    } else {
        int tile = bid - 2048;
        const float* src = xv + ((size_t)(tile >> 4) * SS + (tile & 15) * 64) * DD;
        int row = t >> 2, col = (t & 3) * 16;
#pragma unroll
        for (int ii = 0; ii < 4; ++ii) {
            float4 v = *reinterpret_cast<const float4*>(src + row * DD + col + ii * 4);
            T[row][col + ii*4] = v.x; T[row][col + ii*4 + 1] = v.y;
            T[row][col + ii*4 + 2] = v.z; T[row][col + ii*4 + 3] = v.w;
        }
        __syncthreads();
#pragma unroll
        for (int jj = 0; jj < 2; ++jj) {
            int c2 = t * 2 + jj;
            int lane = c2 & 63, nt = (c2 >> 6) & 3, kc = (c2 >> 8) & 1;
            bf16x8 o;
#pragma unroll
            for (int i = 0; i < 8; ++i)
                o[i] = f2bf(T[kc * 32 + (lane >> 4) * 8 + i][nt * 16 + (lane & 15)]);
            *(reinterpret_cast<bf16x8*>(vfr) + (size_t)tile * 512 + c2) = o;
        }
    }
}

// One block = (b, qt32-pair pp, half, kpar), 8 waves of 512 threads (128-VGPR
// budget -- 1024-thr blocks are compiler-capped at 64 and spilled, R8-R10).
// QB=32: each k-step's K/V bytes serve 32 q rows (R7's L2-BW term halved+).
//  phase1  : wave w: QK^T heads {2w,2w+1}, both 16-row q-subtiles, 4 kt -> P
//  phase1.5: wave w: mix MFMA (16 chunks), store this half's 8 heads -> M
//  phase2  : wave w: softmax + PV for head g = half*8+w, qsub 0 and 1
// Per (b,qt32,kst) phase1+mix run twice (one per half) -- MFMA is cheap; the
// win is V per block = 8 heads (L2 hot set) and K amortized over 32 rows.
__global__ __launch_bounds__(512) void hca_fused(
    const float* __restrict__ xq, const short* __restrict__ kfr,
    const short* __restrict__ vfr, const float* __restrict__ Wm,
    const int* __restrict__ causalp, unsigned short* __restrict__ ppO,
    float2* __restrict__ ppml)
{
    __shared__ int Pbuf[16384];   // 64 KB: P [2048 pos][16 h]
    __shared__ int Mbuf[8192];    // 32 KB: M [8 g][32 q x 32 k-pairs]

    const int tid  = threadIdx.x;
    const int lane = tid & 63;
    const int w    = tid >> 6;     // 0..7
    const int l15  = lane & 15;
    const int lg   = lane >> 4;

    const int bid  = blockIdx.x;   // b(2) | half(1) | pp(4) | kpar(1)
    const int b    = bid & 3;      // b fixed per XCD
    const int half = (bid >> 2) & 1;
    const int pp   = (bid >> 3) & 15;
    const int kpar = (bid >> 7) & 1;

    const int causal = causalp[0];
    const int g = half * 8 + w;    // phase-2 output head

    const float LOG2E = 1.44269504088896f;

    // W B-frag for mix MFMA (K=16 used, zero-padded); lane l15 = output g col
    bf16x8 wt = {0,0,0,0,0,0,0,0};
    if (lg < 2) {
#pragma unroll
        for (int ii = 0; ii < 8; ++ii)
            wt[ii] = f2bf(Wm[l15 * 16 + lg * 8 + ii] * 0.125f * LOG2E);
    }

    const short* vb0 = vfr + (size_t)(b * HH + g) * NKST * 8 * 512 + lane * 8;
    const short* kb0 = kfr + (size_t)(b * HH + 2 * w) * NKST * 8 * 512 + lane * 8;

#pragma unroll 1
    for (int seg = 0; seg < 2; ++seg) {
        const int qt = seg ? pp : 31 - pp;   // pair sums nk(qt)+nk(31-qt)=17
        const int q0 = qt * QB;
        const int pi2 = b * 32 + qt;

        // Q A-frags: heads 2w,2w+1 x qsub x ds (32 VGPR, per-seg constant)
        bf16x8 qf[2][2][2];
#pragma unroll
        for (int hi = 0; hi < 2; ++hi)
#pragma unroll
            for (int qs = 0; qs < 2; ++qs) {
                const float* qp = xq + ((size_t)(b * HH + 2 * w + hi) * SS + q0 + qs * 16 + l15) * DD + lg * 8;
#pragma unroll
                for (int ds = 0; ds < 2; ++ds)
                    qf[hi][qs][ds] = load8_bf16(qp + ds * 32);
            }

        f32x4 oacc[2][4];
#pragma unroll
        for (int qs = 0; qs < 2; ++qs)
#pragma unroll
            for (int nt = 0; nt < 4; ++nt) oacc[qs][nt] = (f32x4){0.f, 0.f, 0.f, 0.f};
        float mrun[2] = {-INFINITY, -INFINITY};
        float lrun[2] = {0.f, 0.f};

        const int nk = causal ? ((q0 + QB + 63) >> 6) : NKST;

#pragma unroll 1
        for (int kst = kpar; kst < nk; kst += 2) {
            const int k0 = kst << 6;

            // ---------- phase1: QK^T heads 2w,2w+1 x 32q x 64k ----------
            __builtin_amdgcn_s_setprio(1);
#pragma unroll
            for (int kt = 0; kt < 4; ++kt) {
                const short* ka = kb0 + (size_t)(kst * 8 + kt * 2) * 512;
                const short* kb = ka + (size_t)NKST * 8 * 512;
                f32x4 a00 = (f32x4){0.f,0.f,0.f,0.f}, a01 = a00, a10 = a00, a11 = a00;
#pragma unroll
                for (int ds = 0; ds < 2; ++ds) {
                    bf16x8 kfa = *reinterpret_cast<const bf16x8*>(ka + ds * 512);
                    bf16x8 kfb = *reinterpret_cast<const bf16x8*>(kb + ds * 512);
                    a00 = __builtin_amdgcn_mfma_f32_16x16x32_bf16(qf[0][0][ds], kfa, a00, 0, 0, 0);
                    a01 = __builtin_amdgcn_mfma_f32_16x16x32_bf16(qf[0][1][ds], kfa, a01, 0, 0, 0);
                    a10 = __builtin_amdgcn_mfma_f32_16x16x32_bf16(qf[1][0][ds], kfb, a10, 0, 0, 0);
                    a11 = __builtin_amdgcn_mfma_f32_16x16x32_bf16(qf[1][1][ds], kfb, a11, 0, 0, 0);
                }
#pragma unroll
                for (int r = 0; r < 4; ++r) {
                    int pos0 = (lg * 4 + r) * 64 + kt * 16 + l15;          // qsub 0
                    int pk0 = (int)(unsigned short)f2bf(a00[r]) | ((int)(unsigned short)f2bf(a10[r]) << 16);
                    Pbuf[pidx(pos0, w)] = pk0;
                    int pos1 = (16 + lg * 4 + r) * 64 + kt * 16 + l15;     // qsub 1
                    int pk1 = (int)(unsigned short)f2bf(a01[r]) | ((int)(unsigned short)f2bf(a11[r]) << 16);
                    Pbuf[pidx(pos1, w)] = pk1;
                }
            }
            __builtin_amdgcn_s_setprio(0);

            // V first half prefetch (covered by sync1 + mix + sync2)
            const short* vbase = vb0 + (size_t)kst * 8 * 512;
            bf16x8 vf0[4];
#pragma unroll
            for (int nt = 0; nt < 4; ++nt)
                vf0[nt] = *reinterpret_cast<const bf16x8*>(vbase + nt * 512);

            __syncthreads();   // sync1: P ready (also fences prev phase2 M-reads)

            // ---------- phase1.5: head-mix MFMA, 16 chunks/wave ----------
#pragma unroll
            for (int m = 0; m < 16; ++m) {
                const int c = w * 16 + m;          // 16-pos chunk; q = c>>2
                const int pos = c * 16 + l15;
                int4 ia = {0, 0, 0, 0};
                if (lg < 2) {
                    ia.x = Pbuf[pidx(pos, lg * 4 + 0)];
                    ia.y = Pbuf[pidx(pos, lg * 4 + 1)];
                    ia.z = Pbuf[pidx(pos, lg * 4 + 2)];
                    ia.w = Pbuf[pidx(pos, lg * 4 + 3)];
                }
                bf16x8 A = __builtin_bit_cast(bf16x8, ia);
                f32x4 cc = (f32x4){0.f, 0.f, 0.f, 0.f};
                cc = __builtin_amdgcn_mfma_f32_16x16x32_bf16(A, wt, cc, 0, 0, 0);
                // lane l15 = g; store only this half's 8 heads
                if ((l15 >> 3) == half) {
                    int q = c >> 2, gl = l15 & 7;
                    int loc = q * 32 + (c & 3) * 8 + lg * 2;
                    int x3 = (q + gl) & 7;
                    int u0 = (int)(unsigned short)f2bf(cc[0]) | ((int)(unsigned short)f2bf(cc[1]) << 16);
                    int u1 = (int)(unsigned short)f2bf(cc[2]) | ((int)(unsigned short)f2bf(cc[3]) << 16);
                    *reinterpret_cast<int2*>(&Mbuf[midx(gl, loc, x3)]) = make_int2(u0, u1);
                }
            }
            __syncthreads();   // sync2: M ready

            // V second half (covered by M-read + softmax)
            bf16x8 vf1[4];
#pragma unroll
            for (int nt = 0; nt < 4; ++nt)
                vf1[nt] = *reinterpret_cast<const bf16x8*>(vbase + (4 + nt) * 512);

            // ---------- phase2: per q-subtile softmax + PV, head g ----------
            const int x3r = (l15 + w) & 7;
#pragma unroll
            for (int qs = 0; qs < 2; ++qs) {
                const int locA = (qs * 16 + l15) * 32 + lg * 4;
                int4 rA = *reinterpret_cast<const int4*>(&Mbuf[midx(w, locA, x3r)]);
                int4 rB = *reinterpret_cast<const int4*>(&Mbuf[midx(w, locA + 16, x3r)]);

                float sm[16];
#pragma unroll
                for (int jj = 0; jj < 4; ++jj) {
                    sm[2*jj]     = bflo(rA[jj]);  sm[2*jj + 1] = bfhi(rA[jj]);
                    sm[8 + 2*jj] = bflo(rB[jj]);  sm[9 + 2*jj] = bfhi(rB[jj]);
                }
                if (causal && kst == nk - 1) {
                    const int qrow = q0 + qs * 16 + l15;
#pragma unroll
                    for (int jj = 0; jj < 16; ++jj) {
                        int kk = (jj < 8) ? (lg * 8 + jj) : (32 + lg * 8 + (jj - 8));
                        if (k0 + kk > qrow) sm[jj] = -INFINITY;
                    }
                }

                float mx[4];
#pragma unroll
                for (int t = 0; t < 4; ++t)
                    mx[t] = fmaxf(fmaxf(sm[4*t], sm[4*t+1]), fmaxf(sm[4*t+2], sm[4*t+3]));
                float mt = fmaxf(fmaxf(mx[0], mx[1]), fmaxf(mx[2], mx[3]));
                mt = fmaxf(mt, __shfl_xor(mt, 16));
                mt = fmaxf(mt, __shfl_xor(mt, 32));

                if (__any(mt > mrun[qs] + 8.0f)) {            // defer-rescale
                    float mnew = fmaxf(mrun[qs], mt);
                    float scl = __builtin_amdgcn_exp2f(mrun[qs] - mnew);
                    mrun[qs] = mnew;
                    lrun[qs] *= scl;
                    int scli = __builtin_bit_cast(int, scl);
#pragma unroll
                    for (int r = 0; r < 4; ++r) {
                        int v = __builtin_amdgcn_ds_bpermute((lg * 4 + r) * 4, scli);
                        float s = __builtin_bit_cast(float, v);
#pragma unroll
                        for (int nt = 0; nt < 4; ++nt) oacc[qs][nt][r] *= s;
                    }
                }

#pragma unroll
                for (int jj = 0; jj < 16; ++jj) sm[jj] = __builtin_amdgcn_exp2f(sm[jj] - mrun[qs]);
                float s0 = ((sm[0]+sm[1]) + (sm[2]+sm[3])) + ((sm[4]+sm[5]) + (sm[6]+sm[7]));
                float s1 = ((sm[8]+sm[9]) + (sm[10]+sm[11])) + ((sm[12]+sm[13]) + (sm[14]+sm[15]));
                lrun[qs] += s0 + s1;

                int paw[8];
#pragma unroll
                for (int t = 0; t < 8; ++t)
                    paw[t] = (int)(unsigned short)f2bf(sm[2*t]) | ((int)(unsigned short)f2bf(sm[2*t+1]) << 16);
                bf16x8 pa0 = __builtin_bit_cast(bf16x8, *(int4*)&paw[0]);
                bf16x8 pa1 = __builtin_bit_cast(bf16x8, *(int4*)&paw[4]);

                __builtin_amdgcn_s_setprio(1);
#pragma unroll
                for (int nt = 0; nt < 4; ++nt)
                    oacc[qs][nt] = __builtin_amdgcn_mfma_f32_16x16x32_bf16(pa0, vf0[nt], oacc[qs][nt], 0, 0, 0);
#pragma unroll
                for (int nt = 0; nt < 4; ++nt)
                    oacc[qs][nt] = __builtin_amdgcn_mfma_f32_16x16x32_bf16(pa1, vf1[nt], oacc[qs][nt], 0, 0, 0);
                __builtin_amdgcn_s_setprio(0);
            }
            // no trailing barrier: sync1(t+1) fences M-reads vs next M-writes;
            // P writes of t+1 are post-sync2(t) in program order for every wave.
        }

        // ---------- epilogue: normalized bf16 partial O + (m,l) ----------
        const size_t gbase = (((size_t)pi2 * 2 + kpar) * 16 + g) * 2048;
#pragma unroll
        for (int qs = 0; qs < 2; ++qs) {
            float lt = lrun[qs];
            lt += __shfl_xor(lt, 16);
            lt += __shfl_xor(lt, 32);
            if (lg == 0)
                ppml[(((size_t)pi2 * 2 + kpar) * 16 + g) * 32 + qs * 16 + l15] =
                    make_float2(mrun[qs], lt);
            float rl = (lt > 0.f) ? (1.0f / lt) : 0.f;
            int rli = __builtin_bit_cast(int, rl);
#pragma unroll
            for (int r = 0; r < 4; ++r) {
                int v = __builtin_amdgcn_ds_bpermute((lg * 4 + r) * 4, rli);
                float linv = __builtin_bit_cast(float, v);
                int q = qs * 16 + lg * 4 + r;
#pragma unroll
                for (int nt = 0; nt < 4; ++nt)
                    ppO[gbase + q * 64 + nt * 16 + l15] =
                        (unsigned short)f2bf(oacc[qs][nt][r] * linv);
            }
        }
        __syncthreads();   // LDS quiesce before next segment reuses P/M
    }
}

// ---------- combine: merge the 2 k-parity partials per (b,qt32) ----------
__global__ __launch_bounds__(256) void hca_combine(
    const unsigned short* __restrict__ ppO, const float2* __restrict__ ppml,
    float* __restrict__ out)
{
    const int pi2 = blockIdx.x;        // b*32 + qt32, 128 blocks
    const int b = pi2 >> 5, qt = pi2 & 31;
    const int t = threadIdx.x;
    const int g = t >> 4, dc = t & 15;

    const size_t o0 = (((size_t)pi2 * 2 + 0) * 16 + g) * 2048;
    const size_t o1 = (((size_t)pi2 * 2 + 1) * 16 + g) * 2048;
    const float2* ml0p = ppml + (((size_t)pi2 * 2 + 0) * 16 + g) * 32;
    const float2* ml1p = ppml + (((size_t)pi2 * 2 + 1) * 16 + g) * 32;

#pragma unroll 4
    for (int q = 0; q < 32; ++q) {
        float2 ml0 = ml0p[q], ml1 = ml1p[q];
        float ms = fmaxf(ml0.x, ml1.x);
        float w0 = ml0.y * exp2f(ml0.x - ms);
        float w1 = ml1.y * exp2f(ml1.x - ms);
        float rs = 1.0f / (w0 + w1);
        float a0 = w0 * rs, a1 = w1 * rs;
        ushort4 u0 = *reinterpret_cast<const ushort4*>(ppO + o0 + q * 64 + dc * 4);
        ushort4 u1 = *reinterpret_cast<const ushort4*>(ppO + o1 + q * 64 + dc * 4);
        float4 res;
        res.x = a0 * bfu(u0.x) + a1 * bfu(u1.x);
        res.y = a0 * bfu(u0.y) + a1 * bfu(u1.y);
        res.z = a0 * bfu(u0.z) + a1 * bfu(u1.z);
        res.w = a0 * bfu(u0.w) + a1 * bfu(u1.w);
        *reinterpret_cast<float4*>(out + (((size_t)b * SS + qt * QB + q) * HH + g) * DD + dc * 4) = res;
    }
}

extern "C" void kernel_launch(void* const* d_in, const int* in_sizes, int n_in,
                              void* d_out, int out_size, void* d_ws, size_t ws_size,
                              hipStream_t stream) {
    const float* xq = (const float*)d_in[0];
    const float* xk = (const float*)d_in[1];
    const float* xv = (const float*)d_in[2];
    const float* Wm = (const float*)d_in[3];
    const int* causal = (const int*)d_in[4];
    float* out = (float*)d_out;

    short* vfr = (short*)d_ws;                               // 8 MB fragment-major V
    short* kfr = vfr + (size_t)NB * HH * SS * DD;            // 8 MB fragment-major K
    unsigned short* ppO = (unsigned short*)(kfr + (size_t)NB * HH * SS * DD);  // 16 MB
    float2* ppml = (float2*)(ppO + (size_t)NB * 32 * 2 * 16 * 2048);           // 1 MB

    prep_all<<<2048 + NB * HH * NKST, 256, 0, stream>>>(xk, kfr, xv, vfr);

    hca_fused<<<256, 512, 0, stream>>>(xq, kfr, vfr, Wm, causal, ppO, ppml);
    hca_combine<<<NB * 32, 256, 0, stream>>>(ppO, ppml, out);
}

// Round 12
// 80.133 us; speedup vs baseline: 1.5880x; 1.2591x over previous
//
#include <hip/hip_runtime.h>
#include <math.h>

#define NB 4
#define HH 16
#define SS 1024
#define DD 64
#define NKST 16   // SS / 64

typedef __attribute__((ext_vector_type(8))) short bf16x8;
typedef __attribute__((ext_vector_type(4))) float f32x4;

static __device__ __forceinline__ short f2bf(float f) {
    __bf16 h = (__bf16)f;
    return __builtin_bit_cast(short, h);
}
static __device__ __forceinline__ float bflo(int w) {
    return __builtin_bit_cast(float, (unsigned)w << 16);
}
static __device__ __forceinline__ float bfhi(int w) {
    return __builtin_bit_cast(float, (unsigned)w & 0xffff0000u);
}
static __device__ __forceinline__ float bfu(unsigned short u) {
    return __builtin_bit_cast(float, (unsigned)u << 16);
}
// P LDS: [pos = q*64 + k][8 u32 head-pairs], XOR swizzle.
static __device__ __forceinline__ int pidx(int pos, int hp) {
    int s = ((pos >> 2) & 3) | (((pos >> 9) & 1) << 2);
    return pos * 8 + (hp ^ s);
}
// M LDS: [16 g][16 q x 32 k-pairs u32], XOR on 16B groups.
static __device__ __forceinline__ int midx(int g, int loc, int x3) {
    return g * 512 + ((((loc >> 2) ^ x3) << 2) | (loc & 3));
}

static __device__ __forceinline__ bf16x8 load8_bf16(const float* p) {
    const float4* p4 = reinterpret_cast<const float4*>(p);
    float4 a = p4[0], b = p4[1];
    bf16x8 f;
    f[0]=f2bf(a.x); f[1]=f2bf(a.y); f[2]=f2bf(a.z); f[3]=f2bf(a.w);
    f[4]=f2bf(b.x); f[5]=f2bf(b.y); f[6]=f2bf(b.z); f[7]=f2bf(b.w);
    return f;
}

// ---------- merged prep: K -> frag-major bf16, V -> frag-major transposed bf16 ----------
__global__ __launch_bounds__(256) void prep_all(const float* __restrict__ xk,
                                                short* __restrict__ kfr,
                                                const float* __restrict__ xv,
                                                short* __restrict__ vfr) {
    __shared__ float T[64][65];
    const int bid = blockIdx.x;
    const int t = threadIdx.x;
    if (bid < 2048) {
        int c = bid * 256 + t;
        int lane = c & 63, ds = (c >> 6) & 1, kt = (c >> 7) & 3;
        int kst = (c >> 9) & 15, h = (c >> 13) & 15, b = c >> 17;
        const float* src = xk + ((size_t)((b * HH + h) * SS) + kst * 64 + kt * 16 + (lane & 15)) * DD
                              + ds * 32 + (lane >> 4) * 8;
        *(reinterpret_cast<bf16x8*>(kfr) + c) = load8_bf16(src);
    } else {
        int tile = bid - 2048;
        const float* src = xv + ((size_t)(tile >> 4) * SS + (tile & 15) * 64) * DD;
        int row = t >> 2, col = (t & 3) * 16;
#pragma unroll
        for (int ii = 0; ii < 4; ++ii) {
            float4 v = *reinterpret_cast<const float4*>(src + row * DD + col + ii * 4);
            T[row][col + ii*4] = v.x; T[row][col + ii*4 + 1] = v.y;
            T[row][col + ii*4 + 2] = v.z; T[row][col + ii*4 + 3] = v.w;
        }
        __syncthreads();
#pragma unroll
        for (int jj = 0; jj < 2; ++jj) {
            int c2 = t * 2 + jj;
            int lane = c2 & 63, nt = (c2 >> 6) & 3, kc = (c2 >> 8) & 1;
            bf16x8 o;
#pragma unroll
            for (int i = 0; i < 8; ++i)
                o[i] = f2bf(T[kc * 32 + (lane >> 4) * 8 + i][nt * 16 + (lane & 15)]);
            *(reinterpret_cast<bf16x8*>(vfr) + (size_t)tile * 512 + c2) = o;
        }
    }
}

// One block = (b, qt, kpar), 16 waves, 64 KB LDS, 64 VGPR -> TWO blocks/CU
// (R11 lesson: resident waves/CU is the dominant predictor; R7's seg loop
// forced grid 256 = 1 block/CU. This is R7's verified kernel minus the seg
// loop, at grid 512.)
//  phase1  : wave w (hp=w&7, kh=w>>3): QK^T heads {2hp,2hp+1}, kt {2kh,2kh+1} -> P
//  phase1.5: wave w: mix MFMA for q-row w (4 chunks) -> M (all 16 g)
//  phase2  : wave w: softmax + PV for g=w -> bf16 partial O + (m,l)
__global__ __launch_bounds__(1024) void hca_fused(
    const float* __restrict__ xq, const short* __restrict__ kfr,
    const short* __restrict__ vfr, const float* __restrict__ Wm,
    const int* __restrict__ causalp, unsigned short* __restrict__ ppO,
    float2* __restrict__ ppml)
{
    __shared__ int Pbuf[8192];   // 32 KB
    __shared__ int Mbuf[8192];   // 32 KB

    const int tid  = threadIdx.x;
    const int lane = tid & 63;
    const int w    = tid >> 6;     // 0..15
    const int l15  = lane & 15;
    const int lg   = lane >> 4;

    // 512 blocks: b(2) | u(6) | r(1). Round r=0 (bids 0..255): qt = 63-u;
    // round r=1: qt = u. kpar = u&1 -> CU c pairs (63-u, !(qt&1)) with
    // (u, qt&1): per-CU step sum ~8.5 for every u, each (qt,kpar) once.
    const int bid  = blockIdx.x;
    const int b    = bid & 3;              // b fixed per XCD
    const int u    = (bid >> 2) & 63;
    const int r    = (bid >> 8) & 1;
    const int qt   = r ? u : 63 - u;
    const int kpar = u & 1;
    const int q0   = qt << 4;
    const int pairIdx = b * 64 + qt;

    const int causal = causalp[0];
    const int hp = w & 7;          // phase-1 head pair
    const int kh = w >> 3;         // phase-1 kt half
    const int g  = w;              // phase-2 output head

    const float LOG2E = 1.44269504088896f;

    // W B-frag for mix MFMA (K=16 used, zero-padded)
    bf16x8 wt = {0,0,0,0,0,0,0,0};
    if (lg < 2) {
#pragma unroll
        for (int ii = 0; ii < 8; ++ii)
            wt[ii] = f2bf(Wm[l15 * 16 + lg * 8 + ii] * 0.125f * LOG2E);
    }

    const short* vb0 = vfr + (size_t)(b * HH + g) * NKST * 8 * 512 + lane * 8;
    const short* kb0 = kfr + (size_t)(b * HH + 2 * hp) * NKST * 8 * 512 + lane * 8;

    // Q A-frags for phase-1 heads (2hp, 2hp+1)
    bf16x8 qf[2][2];
#pragma unroll
    for (int hi = 0; hi < 2; ++hi) {
        const float* qp = xq + ((size_t)(b * HH + 2 * hp + hi) * SS + q0 + l15) * DD + lg * 8;
#pragma unroll
        for (int ds = 0; ds < 2; ++ds) qf[hi][ds] = load8_bf16(qp + ds * 32);
    }

    f32x4 oacc[4];
#pragma unroll
    for (int nt = 0; nt < 4; ++nt) oacc[nt] = (f32x4){0.f, 0.f, 0.f, 0.f};
    float mrun = -INFINITY, lrun = 0.f;

    const int nkf = causal ? ((q0 + 16 + 63) >> 6) : NKST;

#pragma unroll 1
    for (int kst = kpar; kst < nkf; kst += 2) {
        const int k0 = kst << 6;

        // ---------- phase1: QK^T heads 2hp,2hp+1, kt = 2kh, 2kh+1 ----------
        const short* kbase = kb0 + (size_t)kst * 8 * 512;
        __builtin_amdgcn_s_setprio(1);
#pragma unroll
        for (int kt2 = 0; kt2 < 2; ++kt2) {
            const int kt = kh * 2 + kt2;
            f32x4 a0 = (f32x4){0.f,0.f,0.f,0.f}, a1 = a0;
#pragma unroll
            for (int ds = 0; ds < 2; ++ds) {
                bf16x8 kfa = *reinterpret_cast<const bf16x8*>(kbase + (kt*2 + ds) * 512);
                bf16x8 kfb = *reinterpret_cast<const bf16x8*>(kbase + (NKST*8 + kt*2 + ds) * 512);
                a0 = __builtin_amdgcn_mfma_f32_16x16x32_bf16(qf[0][ds], kfa, a0, 0, 0, 0);
                a1 = __builtin_amdgcn_mfma_f32_16x16x32_bf16(qf[1][ds], kfb, a1, 0, 0, 0);
            }
#pragma unroll
            for (int rr = 0; rr < 4; ++rr) {
                int pos = (lg * 4 + rr) * 64 + kt * 16 + l15;
                int pk = (int)(unsigned short)f2bf(a0[rr]) | ((int)(unsigned short)f2bf(a1[rr]) << 16);
                Pbuf[pidx(pos, hp)] = pk;
            }
        }
        __builtin_amdgcn_s_setprio(0);

        // V prefetch (coalesced; lands during mix + barriers)
        const short* vbase = vb0 + (size_t)kst * 8 * 512;
        bf16x8 vf[8];
#pragma unroll
        for (int kc = 0; kc < 2; ++kc)
#pragma unroll
            for (int nt = 0; nt < 4; ++nt)
                vf[kc * 4 + nt] = *reinterpret_cast<const bf16x8*>(vbase + (kc*4 + nt) * 512);

        __syncthreads();   // sync1: P ready (also fences prev phase2 M-reads)

        // ---------- phase1.5: head-mix MFMA; wave w -> q-row w ----------
#pragma unroll
        for (int m = 0; m < 4; ++m) {
            const int c = w * 4 + m;           // pos chunk; q = c>>2 = w
            const int pos = c * 16 + l15;
            int4 ia = {0, 0, 0, 0};
            if (lg < 2) {
                ia.x = Pbuf[pidx(pos, lg * 4 + 0)];
                ia.y = Pbuf[pidx(pos, lg * 4 + 1)];
                ia.z = Pbuf[pidx(pos, lg * 4 + 2)];
                ia.w = Pbuf[pidx(pos, lg * 4 + 3)];
            }
            bf16x8 A = __builtin_bit_cast(bf16x8, ia);
            f32x4 cc = (f32x4){0.f, 0.f, 0.f, 0.f};
            cc = __builtin_amdgcn_mfma_f32_16x16x32_bf16(A, wt, cc, 0, 0, 0);
            // lane: g = l15; q = w, k = (c&3)*16 + lg*4 + r
            int loc = w * 32 + (c & 3) * 8 + lg * 2;
            int x3 = (w + l15) & 7;
            int u0 = (int)(unsigned short)f2bf(cc[0]) | ((int)(unsigned short)f2bf(cc[1]) << 16);
            int u1 = (int)(unsigned short)f2bf(cc[2]) | ((int)(unsigned short)f2bf(cc[3]) << 16);
            *reinterpret_cast<int2*>(&Mbuf[midx(l15, loc, x3)]) = make_int2(u0, u1);
        }
        __syncthreads();   // sync2: M ready

        // ---------- phase2: softmax (log2) + PV for head g = w ----------
        const int x3r = (l15 + g) & 7;
        int4 rA = *reinterpret_cast<const int4*>(&Mbuf[midx(g, l15 * 32 + lg * 4, x3r)]);
        int4 rB = *reinterpret_cast<const int4*>(&Mbuf[midx(g, l15 * 32 + 16 + lg * 4, x3r)]);

        float sm[16];
#pragma unroll
        for (int jj = 0; jj < 4; ++jj) {
            sm[2*jj]     = bflo(rA[jj]);  sm[2*jj + 1] = bfhi(rA[jj]);
            sm[8 + 2*jj] = bflo(rB[jj]);  sm[9 + 2*jj] = bfhi(rB[jj]);
        }
        if (causal && kst == nkf - 1) {
#pragma unroll
            for (int jj = 0; jj < 16; ++jj) {
                int kk = (jj < 8) ? (lg * 8 + jj) : (32 + lg * 8 + (jj - 8));
                if (k0 + kk > q0 + l15) sm[jj] = -INFINITY;
            }
        }

        float mx[4];
#pragma unroll
        for (int t = 0; t < 4; ++t)
            mx[t] = fmaxf(fmaxf(sm[4*t], sm[4*t+1]), fmaxf(sm[4*t+2], sm[4*t+3]));
        float mt = fmaxf(fmaxf(mx[0], mx[1]), fmaxf(mx[2], mx[3]));
        mt = fmaxf(mt, __shfl_xor(mt, 16));
        mt = fmaxf(mt, __shfl_xor(mt, 32));

        if (__any(mt > mrun + 8.0f)) {            // defer-rescale
            float mnew = fmaxf(mrun, mt);
            float scl = __builtin_amdgcn_exp2f(mrun - mnew);
            mrun = mnew;
            lrun *= scl;
            int scli = __builtin_bit_cast(int, scl);
#pragma unroll
            for (int rr = 0; rr < 4; ++rr) {
                int v = __builtin_amdgcn_ds_bpermute((lg * 4 + rr) * 4, scli);
                float s = __builtin_bit_cast(float, v);
#pragma unroll
                for (int nt = 0; nt < 4; ++nt) oacc[nt][rr] *= s;
            }
        }

#pragma unroll
        for (int jj = 0; jj < 16; ++jj) sm[jj] = __builtin_amdgcn_exp2f(sm[jj] - mrun);
        float s0 = ((sm[0]+sm[1]) + (sm[2]+sm[3])) + ((sm[4]+sm[5]) + (sm[6]+sm[7]));
        float s1 = ((sm[8]+sm[9]) + (sm[10]+sm[11])) + ((sm[12]+sm[13]) + (sm[14]+sm[15]));
        lrun += s0 + s1;

        int paw[8];
#pragma unroll
        for (int t = 0; t < 8; ++t)
            paw[t] = (int)(unsigned short)f2bf(sm[2*t]) | ((int)(unsigned short)f2bf(sm[2*t+1]) << 16);
        bf16x8 pa0 = __builtin_bit_cast(bf16x8, *(int4*)&paw[0]);
        bf16x8 pa1 = __builtin_bit_cast(bf16x8, *(int4*)&paw[4]);

        __builtin_amdgcn_s_setprio(1);
#pragma unroll
        for (int nt = 0; nt < 4; ++nt)
            oacc[nt] = __builtin_amdgcn_mfma_f32_16x16x32_bf16(pa0, vf[nt], oacc[nt], 0, 0, 0);
#pragma unroll
        for (int nt = 0; nt < 4; ++nt)
            oacc[nt] = __builtin_amdgcn_mfma_f32_16x16x32_bf16(pa1, vf[4 + nt], oacc[nt], 0, 0, 0);
        __builtin_amdgcn_s_setprio(0);
        // no trailing barrier: sync1(t+1) fences M-reads vs next M-writes;
        // P writes of t+1 are post-sync2(t) in program order for every wave.
    }

    // ---------- epilogue: normalized bf16 partial O + (m,l) ----------
    float lt = lrun;
    lt += __shfl_xor(lt, 16);
    lt += __shfl_xor(lt, 32);
    if (lg == 0)
        ppml[(((size_t)pairIdx * 2 + kpar) * 16 + g) * 16 + l15] = make_float2(mrun, lt);
    float rl = (lt > 0.f) ? (1.0f / lt) : 0.f;
    int rli = __builtin_bit_cast(int, rl);
    size_t obase = (((size_t)pairIdx * 2 + kpar) * 16 + g) * 1024;
#pragma unroll
    for (int rr = 0; rr < 4; ++rr) {
        int v = __builtin_amdgcn_ds_bpermute((lg * 4 + rr) * 4, rli);
        float linv = __builtin_bit_cast(float, v);
        int q = lg * 4 + rr;
#pragma unroll
        for (int nt = 0; nt < 4; ++nt)
            ppO[obase + q * 64 + nt * 16 + l15] =
                (unsigned short)f2bf(oacc[nt][rr] * linv);
    }
}

// ---------- combine: merge the 2 k-parity partials per (b,qt) ----------
__global__ __launch_bounds__(256) void hca_combine(
    const unsigned short* __restrict__ ppO, const float2* __restrict__ ppml,
    float* __restrict__ out)
{
    const int pairIdx = blockIdx.x;        // b*64 + qt
    const int b = pairIdx >> 6, qt = pairIdx & 63;
    const int t = threadIdx.x;
    const int g = t >> 4, dc = t & 15;

    const size_t o0 = (((size_t)pairIdx * 2 + 0) * 16 + g) * 1024;
    const size_t o1 = (((size_t)pairIdx * 2 + 1) * 16 + g) * 1024;
    const float2* ml0p = ppml + (((size_t)pairIdx * 2 + 0) * 16 + g) * 16;
    const float2* ml1p = ppml + (((size_t)pairIdx * 2 + 1) * 16 + g) * 16;

#pragma unroll 4
    for (int q = 0; q < 16; ++q) {
        float2 ml0 = ml0p[q], ml1 = ml1p[q];
        float ms = fmaxf(ml0.x, ml1.x);
        float w0 = ml0.y * exp2f(ml0.x - ms);
        float w1 = ml1.y * exp2f(ml1.x - ms);
        float rs = 1.0f / (w0 + w1);
        float a0 = w0 * rs, a1 = w1 * rs;
        ushort4 u0 = *reinterpret_cast<const ushort4*>(ppO + o0 + q * 64 + dc * 4);
        ushort4 u1 = *reinterpret_cast<const ushort4*>(ppO + o1 + q * 64 + dc * 4);
        float4 res;
        res.x = a0 * bfu(u0.x) + a1 * bfu(u1.x);
        res.y = a0 * bfu(u0.y) + a1 * bfu(u1.y);
        res.z = a0 * bfu(u0.z) + a1 * bfu(u1.z);
        res.w = a0 * bfu(u0.w) + a1 * bfu(u1.w);
        *reinterpret_cast<float4*>(out + (((size_t)b * SS + qt * 16 + q) * HH + g) * DD + dc * 4) = res;
    }
}

extern "C" void kernel_launch(void* const* d_in, const int* in_sizes, int n_in,
                              void* d_out, int out_size, void* d_ws, size_t ws_size,
                              hipStream_t stream) {
    const float* xq = (const float*)d_in[0];
    const float* xk = (const float*)d_in[1];
    const float* xv = (const float*)d_in[2];
    const float* Wm = (const float*)d_in[3];
    const int* causal = (const int*)d_in[4];
    float* out = (float*)d_out;

    short* vfr = (short*)d_ws;                               // 8 MB fragment-major V
    short* kfr = vfr + (size_t)NB * HH * SS * DD;            // 8 MB fragment-major K
    unsigned short* ppO = (unsigned short*)(kfr + (size_t)NB * HH * SS * DD);  // 16 MB
    float2* ppml = (float2*)(ppO + (size_t)512 * 16 * 1024); // 1 MB

    prep_all<<<2048 + NB * HH * NKST, 256, 0, stream>>>(xk, kfr, xv, vfr);

    hca_fused<<<512, 1024, 0, stream>>>(xq, kfr, vfr, Wm, causal, ppO, ppml);
    hca_combine<<<256, 256, 0, stream>>>(ppO, ppml, out);
}